// Round 7
// baseline (318.582 us; speedup 1.0000x reference)
//
#include <hip/hip_runtime.h>
#include <math.h>

// Problem shape (fixed by reference setup_inputs):
//   images [32][256][64][64] fp32, words [32][32][768] fp32, mask [32][32] bool,
//   W [256][768] fp32, b [256] fp32
//   out0 weighted_words [32][256][64][64], out1 attn_out [32][32][64][64], fp32 concat.
#define B_   32
#define NC_  256
#define HW_  4096
#define MW_  32
#define E_   768
#define NEG_BIG -3.0e38f

// Native Clang vector types: __builtin_nontemporal_* accepts these
// (HIP's float2/float4 are classes and are rejected -- R5 compile failure).
typedef float vf2 __attribute__((ext_vector_type(2)));
typedef float vf4 __attribute__((ext_vector_type(4)));

// Workspace layout (float offsets).
#define PART_OFF   0          // partial GEMM: 8 chunks * 32b * 32m * 256c = 2097152 floats
#define WT_OFF     2359296    // W transposed [e][c]: 196608 floats
#define WORDST_OFF 2555904    // words transposed [b][e][m]: 786432 floats

// ---------------------------------------------------------------------------
// Prep: tiled transposes only (W 256x768 -> WT 768x256; words[b] 32x768 ->
// wordsT[b] 768x32). Mask handling moved into attention (R7).
// Blocks 0..191: W transpose. 192..959: words transpose.
// ---------------------------------------------------------------------------
__global__ __launch_bounds__(256) void prep_kernel(
    const float* __restrict__ W, const float* __restrict__ words,
    float* __restrict__ WT, float* __restrict__ wordsT) {
  const int tid = threadIdx.x;
  const int tx = tid & 31, ty = tid >> 5;
  if (blockIdx.x < 192) {
    // W: 32x32 tile transpose; tiles: 8 (c) x 24 (e)
    __shared__ float t[32][33];
    const int tc = blockIdx.x / 24, te = blockIdx.x % 24;
    const int c0 = tc * 32, e0 = te * 32;
#pragma unroll
    for (int k = 0; k < 4; ++k) {
      const int r = ty + 8 * k;
      t[r][tx] = W[(c0 + r) * E_ + e0 + tx];  // coalesced over tx
    }
    __syncthreads();
#pragma unroll
    for (int k = 0; k < 4; ++k) {
      const int r = ty + 8 * k;
      WT[(e0 + r) * NC_ + c0 + tx] = t[tx][r];  // coalesced over tx
    }
  } else {
    // words[b]: 32(m) x 768(e) -> wordsT[b]: 768(e) x 32(m). tiles: 32 b x 24 e
    __shared__ float t[32][33];
    const int idx = blockIdx.x - 192;
    const int b = idx / 24, te = idx % 24;
    const int e0 = te * 32;
    const float* wsrc = words + (size_t)b * MW_ * E_;
    float* wdst = wordsT + (size_t)b * E_ * MW_;
#pragma unroll
    for (int k = 0; k < 4; ++k) {
      const int m = ty + 8 * k;
      t[m][tx] = wsrc[m * E_ + e0 + tx];        // coalesced over tx (e)
    }
    __syncthreads();
#pragma unroll
    for (int k = 0; k < 4; ++k) {
      const int e = ty + 8 * k;
      wdst[(e0 + e) * MW_ + tx] = t[tx][e];     // coalesced over tx (m)
    }
  }
}

// ---------------------------------------------------------------------------
// Stage 1a: words_p partials. Block = (batch, e-chunk of 96). lane = c.
// (Reduction + bias now fused into attention's LDS staging.)
// ---------------------------------------------------------------------------
__global__ __launch_bounds__(256) void stage1_partial(
    const float* __restrict__ wordsT, const float* __restrict__ WT,
    float* __restrict__ part) {
  const int c = threadIdx.x;
  const int b = blockIdx.x >> 3;
  const int chunk = blockIdx.x & 7;
  const int e0 = chunk * 96;
  const float* wt = wordsT + (size_t)b * E_ * MW_;
  float acc[32];
#pragma unroll
  for (int m = 0; m < 32; ++m) acc[m] = 0.f;
#pragma unroll 2
  for (int e = e0; e < e0 + 96; ++e) {
    const float wv = WT[(size_t)e * NC_ + c];   // coalesced over lanes
    const float* wr = wt + e * MW_;             // uniform, contiguous
#pragma unroll
    for (int m = 0; m < 32; ++m) acc[m] = fmaf(wv, wr[m], acc[m]);
  }
  float* pp = part + ((size_t)chunk * 32 + b) * 32 * 256;
#pragma unroll
  for (int m = 0; m < 32; ++m) pp[m * 256 + c] = acc[m];  // coalesced
}

// ---------------------------------------------------------------------------
// Stage 2 (R7): LDS-wp + 2 px/thread + in-kernel partial-reduce + explicit
// wrow register double-buffer.
// History:
//   R0 (128us): wp via s_load -> scalar-stream stall, 21% duty/wave.
//   R1-R3: c-split spills. Abandoned.
//   R4 (102us): wp in LDS (1px/thr, 8 waves/CU): LDS-pipe bound, 47% VALU.
//   R6 (94us): 2px/thr halves LDS:FMA ratio but also halves waves (4/CU,
//       1/SIMD): per-wave duty 23->50%, total flat. 50% = latency bubbles
//       with zero TLP cover.
// R7 changes:
//   a) stage1_reduce fused here: each thread owns 2 channel rows; reads
//      8 partials+bias (coalesced b32, part is L2/L3-resident 8MB), writes
//      its rows as b128s. Deletes a kernel+node+wp round trip. (~+1us here,
//      -4us kernel, -1 launch node.)
//   b) raw-mask decode in-kernel (same layout detection as old prep block).
//   c) score & PV loops: explicit LDS->reg ping-pong for wrow -- channel
//      j+1's 8 ds_read_b128 issued before channel j's 64 FMAs, so ~120cy
//      LDS latency hides under the 128cy FMA block even at 1 wave/SIMD.
//      All indices static (full unroll) -> registers, no scratch.
//   d) img prefetch 8-deep (1024 FMA-cyc cover > ~900cy HBM) to keep
//      VGPR ~180-200 (1 wave/SIMD needs <=512; no launch-bounds minimum).
// ---------------------------------------------------------------------------
__global__ __launch_bounds__(128) void attention_fused(
    const float* __restrict__ images, const float* __restrict__ part,
    const float* __restrict__ bias, const void* __restrict__ mask_raw,
    float* __restrict__ out_w, float* __restrict__ out_a) {
  __shared__ float lwp[NC_ * MW_];  // [c][m], 32 KB
  __shared__ int is_word;
  const int tid = threadIdx.x;           // 0..127
  const int b = blockIdx.x & 31;         // batch-minor: XCD-mates share b
  const int po = ((blockIdx.x >> 5) << 7) + tid;  // vf2 idx in [0,2048)
  const vf2* imgb = (const vf2*)(images + (size_t)b * NC_ * HW_);

  if (tid == 0) is_word = 1;

  // Issue image prefetch FIRST -- flies during the staging below.
  vf2 cur[8];
#pragma unroll
  for (int j = 0; j < 8; ++j)
    cur[j] = __builtin_nontemporal_load(&imgb[((size_t)j << 11) + po]);

  // Staging-reduce: lwp[c][m] = bias[c] + sum_k part[k][b][m][c].
  // Thread owns channels c = tid and tid+128. Reads coalesced over lanes.
#pragma unroll
  for (int half = 0; half < 2; ++half) {
    const int c = (half << 7) + tid;
    const float bc = bias[c];
    float row[32];
#pragma unroll
    for (int m = 0; m < 32; ++m) row[m] = bc;
#pragma unroll
    for (int k = 0; k < 8; ++k) {
      const float* pk = part + (((size_t)k * 32 + b) * 32) * 256 + c;
#pragma unroll
      for (int m = 0; m < 32; ++m) row[m] += pk[(size_t)m * 256];
    }
    vf4* dst = (vf4*)(lwp + (c << 5));
#pragma unroll
    for (int q = 0; q < 8; ++q) {
      vf4 t;
      t.x = row[4 * q]; t.y = row[4 * q + 1];
      t.z = row[4 * q + 2]; t.w = row[4 * q + 3];
      dst[q] = t;
    }
  }
  __syncthreads();  // lwp ready; is_word init visible

  // Mask layout detection (reads only first 1024 bytes: safe for any layout).
  {
    const int* mi = (const int*)mask_raw;
#pragma unroll
    for (int q = 0; q < 2; ++q) {
      const int v = mi[q * 128 + tid];
      if (v != 0 && v != 1 && v != 0x3F800000) is_word = 0;
    }
  }
  __syncthreads();
  unsigned mbits = 0;
  if (is_word) {
    const int* mi = (const int*)mask_raw;
#pragma unroll
    for (int m = 0; m < 32; ++m)
      mbits |= (mi[(b << 5) + m] != 0 ? 1u : 0u) << m;
  } else {
    const unsigned char* mb = (const unsigned char*)mask_raw;
#pragma unroll
    for (int m = 0; m < 32; ++m)
      mbits |= (mb[(b << 5) + m] != 0 ? 1u : 0u) << m;
  }

  // ---- score loop: s{0,1}[m] = sum_c img[c][p{0,1}] * wp[c][m] ----
  float s0[32], s1[32];
#pragma unroll
  for (int m = 0; m < 32; ++m) { s0[m] = 0.f; s1[m] = 0.f; }

  vf4 wa[8], wb[8];
#pragma unroll
  for (int q = 0; q < 8; ++q) wa[q] = ((const vf4*)lwp)[q];  // channel 0

#pragma unroll 1
  for (int c0 = 0; c0 < 256; c0 += 8) {
    vf2 nxt[8];
    if (c0 + 8 < 256) {
#pragma unroll
      for (int j = 0; j < 8; ++j)
        nxt[j] = __builtin_nontemporal_load(&imgb[((size_t)(c0 + 8 + j) << 11) + po]);
    }
#pragma unroll
    for (int j = 0; j < 8; ++j) {
      const int cn = c0 + j + 1;  // next channel to prefetch
      // static ping-pong: even channels live in wa, odd in wb
      if ((j & 1) == 0) {
        if (cn < 256) {
#pragma unroll
          for (int q = 0; q < 8; ++q) wb[q] = ((const vf4*)lwp)[(cn << 3) + q];
        }
        const float* wr = (const float*)wa;
        const vf2 v = cur[j];
#pragma unroll
        for (int m = 0; m < 32; ++m) {
          s0[m] = fmaf(v.x, wr[m], s0[m]);
          s1[m] = fmaf(v.y, wr[m], s1[m]);
        }
      } else {
        if (cn < 256) {
#pragma unroll
          for (int q = 0; q < 8; ++q) wa[q] = ((const vf4*)lwp)[(cn << 3) + q];
        }
        const float* wr = (const float*)wb;
        const vf2 v = cur[j];
#pragma unroll
        for (int m = 0; m < 32; ++m) {
          s0[m] = fmaf(v.x, wr[m], s0[m]);
          s1[m] = fmaf(v.y, wr[m], s1[m]);
        }
      }
    }
#pragma unroll
    for (int j = 0; j < 8; ++j) cur[j] = nxt[j];  // dead on last iter
  }

  // ---- softmax over m for both pixels (scale 1/sqrt(256)) ----
  float mx0 = NEG_BIG, mx1 = NEG_BIG;
#pragma unroll
  for (int m = 0; m < 32; ++m) {
    s0[m] *= 0.0625f;
    s1[m] *= 0.0625f;
    if (!((mbits >> m) & 1u)) {
      mx0 = fmaxf(mx0, s0[m]);
      mx1 = fmaxf(mx1, s1[m]);
    }
  }
  float sum0 = 0.f, sum1 = 0.f;
#pragma unroll
  for (int m = 0; m < 32; ++m) {
    const bool msk = (mbits >> m) & 1u;
    const float e0 = msk ? 0.f : __expf(s0[m] - mx0);
    const float e1 = msk ? 0.f : __expf(s1[m] - mx1);
    s0[m] = e0; s1[m] = e1;
    sum0 += e0; sum1 += e1;
  }
  const float inv0 = 1.f / sum0, inv1 = 1.f / sum1;
  vf2* oa = (vf2*)out_a;
#pragma unroll
  for (int m = 0; m < 32; ++m) {
    s0[m] *= inv0;
    s1[m] *= inv1;
    vf2 a; a.x = s0[m]; a.y = s1[m];
    __builtin_nontemporal_store(a, &oa[((size_t)((b << 5) + m) << 11) + po]);
  }

  // ---- PV loop: out[c][p] = sum_m wp[c][m] * a[m] (same wrow ping-pong) ----
  vf2* ow = (vf2*)out_w;
#pragma unroll
  for (int q = 0; q < 8; ++q) wa[q] = ((const vf4*)lwp)[q];  // channel 0

#pragma unroll 1
  for (int c0 = 0; c0 < 256; c0 += 8) {
#pragma unroll
    for (int j = 0; j < 8; ++j) {
      const int c = c0 + j;
      const int cn = c + 1;
      float o0 = 0.f, o1 = 0.f;
      if ((j & 1) == 0) {
        if (cn < 256) {
#pragma unroll
          for (int q = 0; q < 8; ++q) wb[q] = ((const vf4*)lwp)[(cn << 3) + q];
        }
        const float* wr = (const float*)wa;
#pragma unroll
        for (int m = 0; m < 32; ++m) {
          o0 = fmaf(wr[m], s0[m], o0);
          o1 = fmaf(wr[m], s1[m], o1);
        }
      } else {
        if (cn < 256) {
#pragma unroll
          for (int q = 0; q < 8; ++q) wa[q] = ((const vf4*)lwp)[(cn << 3) + q];
        }
        const float* wr = (const float*)wb;
#pragma unroll
        for (int m = 0; m < 32; ++m) {
          o0 = fmaf(wr[m], s0[m], o0);
          o1 = fmaf(wr[m], s1[m], o1);
        }
      }
      vf2 o; o.x = o0; o.y = o1;
      __builtin_nontemporal_store(o, &ow[((size_t)((b << 8) + c) << 11) + po]);
    }
  }
}

// ---------------------------------------------------------------------------
extern "C" void kernel_launch(void* const* d_in, const int* in_sizes, int n_in,
                              void* d_out, int out_size, void* d_ws, size_t ws_size,
                              hipStream_t stream) {
  const float* images = (const float*)d_in[0];
  const float* words  = (const float*)d_in[1];
  const void*  mask   = d_in[2];
  const float* W      = (const float*)d_in[3];
  const float* bias   = (const float*)d_in[4];

  float* ws     = (float*)d_ws;
  float* part   = ws + PART_OFF;
  float* WT     = ws + WT_OFF;
  float* wordsT = ws + WORDST_OFF;

  float* out_w = (float*)d_out;
  float* out_a = out_w + (size_t)B_ * NC_ * HW_;

  prep_kernel<<<960, 256, 0, stream>>>(W, words, WT, wordsT);
  stage1_partial<<<256, 256, 0, stream>>>(wordsT, WT, part);
  attention_fused<<<512, 128, 0, stream>>>(images, part, bias, mask, out_w, out_a);
}